// Round 7
// baseline (290.530 us; speedup 1.0000x reference)
//
#include <hip/hip_runtime.h>
#include <math.h>

// ExodusNeuron: per-(b,n) sequential scan over T with spike threshold/reset.
// x: (B=32, T=2048, N=512, 1) fp32; weight: (1,1) fp32; out: (B,T,N,1) fp32.
//
// R10: page-granularity fix — blocks own CONTIGUOUS half-rows.
//   Evidence: R3/R7/R8/R9 varied load path, depth, store width/type, wave
//   roles — ALL converge at 2.35-2.44 TB/s DRAM (85us). The invariant is
//   the address pattern: 64-neuron columns -> every wave access is a
//   256B segment at 2KB stride. HBM page ~1KB: 256B/activation caps
//   efficiency ~30% (writes measured 1.54 TB/s vs fillBuffer's 6.6).
//   Sibling blocks sharing a row sat on DIFFERENT XCDs (blk%8), so
//   sub-page requests never merged. Fix:
//     - 64 blocks x 256 neurons (half-row): every DMA read and every
//       store is 1KB CONTIGUOUS per instruction (64 lanes x 16B).
//     - b=blk&31, h=blk>>5: siblings {blk,blk+32} land on the SAME XCD
//       ((b+32)%8==b%8) -> the two half-pages merge in one L2/queue.
//   Skeleton = R9's proven 3-role design, scaled:
//     wave 0-3: consumers (64 neurons each, LDS in -> compute -> LDS out)
//     wave 4:   DMA producer, width-16 global_load_lds, depth-3,
//               counted vmcnt(32), never 0 mid-loop
//     wave 5:   writer, 16x global_store_dwordx4 (1KB each) per tile
//   TILE=16 rows, NTILE=128, NBUF=4 (96KB LDS total), raw s_barrier +
//   sched_barrier(0) fences + lgkmcnt(0) for cross-wave LDS visibility.
//
// Numerics MUST match numpy's fp32 rounding exactly (outputs are 0/1 spikes;
// a flipped spike = absmax 1.0): separate rounded mul/add (no FMA), and
// alpha = correctly-rounded float of exp(double(float(-0.05))).
// fire ? __fsub_rn(va,1.0f) : va is bitwise identical to va - spk.
// R0-R9 all passed with absmax == 0.0 — per-lane arithmetic unchanged
// (only the lane->(b,n) mapping changed).

constexpr int T_ = 2048;
constexpr int N_ = 512;
constexpr int NSPAN = 256;           // neurons per block (contiguous half-row)
constexpr int TILE = 16;             // time rows per tile
constexpr int NTILE = T_ / TILE;     // 128 tiles
constexpr int NBUF = 4;              // XBUF ring (reader + 3 in flight)

typedef const __attribute__((address_space(1))) void* gas_ptr;
typedef __attribute__((address_space(3))) void* las_ptr;

__global__ __launch_bounds__(384, 1)
void exodus_row_kernel(const float* __restrict__ x,
                       const float* __restrict__ wptr,
                       float* __restrict__ out) {
    __shared__ __align__(16) float XBUF[NBUF][TILE][NSPAN];  // 64 KB input
    __shared__ __align__(16) float SBUF[2][TILE][NSPAN];     // 32 KB spikes

    const int blk  = blockIdx.x;        // 0..63
    const int b    = blk & 31;          // batch
    const int h    = blk >> 5;          // half-row; siblings share XCD
    const int wave = threadIdx.x >> 6;  // 0-3 consumer, 4 producer, 5 writer
    const int lane = threadIdx.x & 63;

    const size_t rowbase = (size_t)b * T_ * N_ + (size_t)h * NSPAN;

    if (wave == 4) {
        // ========== producer: 1KB-contiguous DMA rows, depth-3 ===========
        // One global_load_lds width=16 per time-row: 64 lanes x 16B = 1KB
        // contiguous. LDS dest linear (base + lane*16) matches layout.
        const float* __restrict__ gl = x + rowbase + (size_t)lane * 4;

#define ISSUE_TILE(TT)                                                        \
        {                                                                     \
            const float* __restrict__ g_ =                                    \
                gl + (size_t)(TT) * TILE * N_;                                \
            _Pragma("unroll")                                                 \
            for (int j_ = 0; j_ < TILE; ++j_) {                               \
                __builtin_amdgcn_global_load_lds(                             \
                    (gas_ptr)(g_ + (size_t)j_ * N_),                          \
                    (las_ptr)&XBUF[(TT) & (NBUF - 1)][j_][0], 16, 0, 0);      \
            }                                                                 \
        }

        // prologue: tiles 0,1,2 in flight (48 DMAs); confirm tile 0 only.
        ISSUE_TILE(0);
        ISSUE_TILE(1);
        ISSUE_TILE(2);
        __builtin_amdgcn_sched_barrier(0);
        asm volatile("s_waitcnt vmcnt(32)");   // tile 0 landed; 1,2 fly
        __builtin_amdgcn_sched_barrier(0);
        __builtin_amdgcn_s_barrier();          // barrier 0

        for (int t = 0; t < NTILE; ++t) {
            if (t + 3 < NTILE) {
                ISSUE_TILE(t + 3);
                __builtin_amdgcn_sched_barrier(0);
                // outstanding = 48 (t+1,t+2,t+3); confirm oldest 16 = t+1.
                asm volatile("s_waitcnt vmcnt(32)");
            } else {
                // tail (last 3 intervals): conservative drain is fine here.
                asm volatile("s_waitcnt vmcnt(0)");
            }
            __builtin_amdgcn_sched_barrier(0);
            __builtin_amdgcn_s_barrier();
        }
#undef ISSUE_TILE
    } else if (wave == 5) {
        // ========== writer: SBUF -> global, 16x 1KB dwordx4 per tile ======
        float* __restrict__ ow = out + rowbase + (size_t)lane * 4;

        __builtin_amdgcn_s_barrier();          // barrier 0

        for (int t = 0; t < NTILE; ++t) {
            if (t >= 1) {
                const int sb = (t - 1) & 1;
                float4 v[TILE];
#pragma unroll
                for (int j = 0; j < TILE; ++j)
                    v[j] = *(const float4*)&SBUF[sb][j][lane * 4];
                float* __restrict__ o = ow + (size_t)(t - 1) * TILE * N_;
#pragma unroll
                for (int j = 0; j < TILE; ++j)
                    *(float4*)(o + (size_t)j * N_) = v[j];
            }
            __builtin_amdgcn_sched_barrier(0);
            // SBUF reads must retire before consumer overwrites this half.
            asm volatile("s_waitcnt lgkmcnt(0)");
            __builtin_amdgcn_sched_barrier(0);
            __builtin_amdgcn_s_barrier();
        }
        // epilogue: tile NTILE-1 (after final barrier)
        {
            const int sb = (NTILE - 1) & 1;
            float4 v[TILE];
#pragma unroll
            for (int j = 0; j < TILE; ++j)
                v[j] = *(const float4*)&SBUF[sb][j][lane * 4];
            float* __restrict__ o = ow + (size_t)(NTILE - 1) * TILE * N_;
#pragma unroll
            for (int j = 0; j < TILE; ++j)
                *(float4*)(o + (size_t)j * N_) = v[j];
        }
    } else {
        // ========== consumers: LDS in -> scan -> LDS out ==================
        const int col = wave * 64 + lane;      // 0..255 within half-row
        const float w = wptr[0];
        const float alpha = (float)exp((double)(-1.0f / 20.0f));
        float vsyn = 0.0f, vmem = 0.0f;

        __builtin_amdgcn_s_barrier();          // barrier 0 (tile 0 ready)

        for (int t = 0; t < NTILE; ++t) {
            const int xb = t & (NBUF - 1);
            const int sb = t & 1;
            __builtin_amdgcn_sched_barrier(0);

            // stride-1KB LDS reads: bank = col%32 both halves -> 2-way, free
            float xv[TILE];
#pragma unroll
            for (int j = 0; j < TILE; ++j) xv[j] = XBUF[xb][j][col];

#pragma unroll
            for (int j = 0; j < TILE; ++j) {
                const float i_t = __fmul_rn(xv[j], w);
                vsyn = __fadd_rn(__fmul_rn(alpha, vsyn), i_t);
                const float va = __fadd_rn(__fmul_rn(alpha, vmem), vsyn);
                const bool fire = (va >= 1.0f);
                SBUF[sb][j][col] = fire ? 1.0f : 0.0f;
                vmem = fire ? __fsub_rn(va, 1.0f) : va;   // == va - spk
            }
            __builtin_amdgcn_sched_barrier(0);
            // publish spikes before the raw barrier (no implicit drain).
            asm volatile("s_waitcnt lgkmcnt(0)");
            __builtin_amdgcn_sched_barrier(0);
            __builtin_amdgcn_s_barrier();
        }
    }
}

extern "C" void kernel_launch(void* const* d_in, const int* in_sizes, int n_in,
                              void* d_out, int out_size, void* d_ws, size_t ws_size,
                              hipStream_t stream) {
    const float* x = (const float*)d_in[0];
    const float* w = (const float*)d_in[1];
    float* out = (float*)d_out;

    dim3 grid(64);     // 32 batches x 2 half-rows; siblings share an XCD
    dim3 block(384);   // waves 0-3 consumers, 4 DMA producer, 5 writer
    hipLaunchKernelGGL(exodus_row_kernel, grid, block, 0, stream, x, w, out);
}

// Round 8
// 245.953 us; speedup vs baseline: 1.1812x; 1.1812x over previous
//
#include <hip/hip_runtime.h>
#include <math.h>

// ExodusNeuron: per-(b,n) sequential scan over T with spike threshold/reset.
// x: (B=32, T=2048, N=512, 1) fp32; weight: (1,1) fp32; out: (B,T,N,1) fp32.
//
// R11: multi-stream memory waves (4 producers + 2 writers + 1 consumer).
//   Evidence: R9 (2 VMEM waves/CU) = 9.2 GB/s/CU; R10 (same structure,
//   1KB-contiguous, 64 CUs) = 23.5 GB/s/CU == m13's per-CU streaming
//   ceiling (6.3TB/s / 256). R10 proved per-CU service can be ~24 GB/s
//   but idled 3/4 of the machine (geometry: chunk x blocks = 16384 fixed;
//   time-split fails because LDS can't buffer a quarter -> serializes).
//   Untested lever: per-CU INDEPENDENT stream count. vmcnt is per-wave,
//   in-order -> head-of-line blocking caps one wave's stream (R8's
//   deeper-queue-in-one-wave null is consistent). m13 ran ~8 streaming
//   waves/CU. Here: 7 waves/block on 256 blocks:
//     wave 0:    consumer (scan, LDS in -> LDS out, no global traffic)
//     waves 1-4: producers; producer p owns tiles t%4==p, its own
//                width-16 global_load_lds stream, counted vmcnt(8),
//                issue lead 7 tiles (XBUF ring = 8)
//     waves 5-6: writers; alternate tiles, SBUF -> 8x dwordx4 (1KB) each,
//                stores never waited (natural backpressure)
//   TILE=32 rows, 64 intervals, raw s_barrier per interval,
//   sched_barrier(0) fences, lgkmcnt(0) for cross-wave LDS visibility.
//
// Numerics MUST match numpy's fp32 rounding exactly (outputs are 0/1 spikes;
// a flipped spike = absmax 1.0): separate rounded mul/add (no FMA), and
// alpha = correctly-rounded float of exp(double(float(-0.05))).
// fire ? __fsub_rn(va,1.0f) : va is bitwise identical to va - spk.
// R0-R10 all passed with absmax == 0.0 — do not change the arithmetic.

constexpr int T_ = 2048;
constexpr int N_ = 512;
constexpr int TILE = 32;             // time rows per tile
constexpr int NTILE = T_ / TILE;     // 64 tiles
constexpr int NCH = 64;              // neurons per block
constexpr int NXB = 8;               // XBUF ring depth
constexpr int NSB = 4;               // SBUF ring depth

typedef const __attribute__((address_space(1))) void* gas_ptr;
typedef __attribute__((address_space(3))) void* las_ptr;

#define SB() __builtin_amdgcn_sched_barrier(0)

__global__ __launch_bounds__(448, 1)
void exodus_ms_kernel(const float* __restrict__ x,
                      const float* __restrict__ wptr,
                      float* __restrict__ out) {
    __shared__ __align__(16) float XBUF[NXB][TILE][NCH];  // 64 KB input ring
    __shared__ __align__(16) float SBUF[NSB][TILE][NCH];  // 32 KB spike ring

    const int blk  = blockIdx.x;        // 0..255
    const int b    = blk >> 3;          // 0..31
    const int n0   = (blk & 7) * NCH;   // 0,64,...,448
    const int wave = threadIdx.x >> 6;  // 0 cons, 1-4 prod, 5-6 writer
    const int lane = threadIdx.x & 63;

    if (wave >= 1 && wave <= 4) {
        // ================= producers: 4 independent DMA streams ===========
        const int p = wave - 1;               // 0..3, owns tiles t%4==p
        // width-16 DMA: lane l = 16B of time-row (l>>4) in each 4-row
        // group; one instr = 4 rows (1KB). 8 instrs per 32-row tile.
        const int plane = lane >> 4;
        const int sub   = lane & 15;
        const float* __restrict__ gl =
            x + (size_t)b * T_ * N_ + (size_t)plane * N_ + n0 + sub * 4;

#define ISSUE_TILE(TT)                                                        \
        {                                                                     \
            const float* __restrict__ g_ =                                    \
                gl + (size_t)(TT) * TILE * N_;                                \
            _Pragma("unroll")                                                 \
            for (int r_ = 0; r_ < TILE; r_ += 4) {                            \
                __builtin_amdgcn_global_load_lds(                             \
                    (gas_ptr)(g_ + (size_t)r_ * N_),                          \
                    (las_ptr)&XBUF[(TT) & (NXB - 1)][r_][0], 16, 0, 0);       \
            }                                                                 \
        }

        // prologue: issue tiles p and p+4; confirm tile p (oldest 8).
        ISSUE_TILE(p);
        ISSUE_TILE(p + 4);
        SB();
        asm volatile("s_waitcnt vmcnt(8)");
        SB();
        __builtin_amdgcn_s_barrier();          // barrier 0

        for (int k = 0; k < NTILE; ++k) {
            // producer p acts at k ≡ p+1 (mod 4): issues tile k+7 (slot
            // (k+7)&7 freed at end of interval k-1) and confirms its
            // previous tile k+3 (needed at interval k+3).
            if ((k & 3) == ((p + 1) & 3)) {
                if (k + 7 < NTILE) {
                    ISSUE_TILE(k + 7);
                    SB();
                    asm volatile("s_waitcnt vmcnt(8)");   // confirm tile k+3
                } else {
                    SB();
                    asm volatile("s_waitcnt vmcnt(0)");   // tail confirm
                }
                SB();
            }
            __builtin_amdgcn_s_barrier();
        }
#undef ISSUE_TILE
    } else if (wave >= 5) {
        // ================= writers: 2 alternating store streams ==========
        const int wbit = wave - 5;            // 0 or 1; owns tiles j%2==wbit
        const int plane = lane >> 4;          // 4 rows per store instr
        const int sub   = lane & 15;
        float* __restrict__ ow =
            out + (size_t)b * T_ * N_ + (size_t)plane * N_ + n0 + sub * 4;

        __builtin_amdgcn_s_barrier();          // barrier 0

        for (int k = 0; k < NTILE; ++k) {
            if (k >= 1 && ((k - 1) & 1) == wbit) {
                const int j = k - 1;           // tile to drain
                const int sb = j & (NSB - 1);
                float4 v[TILE / 4];
#pragma unroll
                for (int g = 0; g < TILE / 4; ++g)
                    v[g] = *(const float4*)&SBUF[sb][4 * g + plane][sub * 4];
                float* __restrict__ o = ow + (size_t)j * TILE * N_;
#pragma unroll
                for (int g = 0; g < TILE / 4; ++g)
                    *(float4*)(o + (size_t)(4 * g) * N_) = v[g];
                SB();
                // SBUF reads must retire before consumer reuses the slot;
                // stores fly uncounted (backpressure only).
                asm volatile("s_waitcnt lgkmcnt(0)");
                SB();
            }
            __builtin_amdgcn_s_barrier();
        }
        // epilogue: tile NTILE-1 ((NTILE-1)&1 == 1 -> wave 6), after the
        // final barrier (consumer published + lgkmcnt(0) before it).
        if (wbit == ((NTILE - 1) & 1)) {
            const int j = NTILE - 1;
            const int sb = j & (NSB - 1);
            float4 v[TILE / 4];
#pragma unroll
            for (int g = 0; g < TILE / 4; ++g)
                v[g] = *(const float4*)&SBUF[sb][4 * g + plane][sub * 4];
            float* __restrict__ o = ow + (size_t)j * TILE * N_;
#pragma unroll
            for (int g = 0; g < TILE / 4; ++g)
                *(float4*)(o + (size_t)(4 * g) * N_) = v[g];
        }
    } else {
        // ================= consumer: the scan ============================
        const float w = wptr[0];
        const float alpha = (float)exp((double)(-1.0f / 20.0f));
        float vsyn = 0.0f, vmem = 0.0f;

        __builtin_amdgcn_s_barrier();          // barrier 0 (tile 0 ready)

        for (int k = 0; k < NTILE; ++k) {
            const int xb = k & (NXB - 1);
            const int sb = k & (NSB - 1);
            SB();

            float xv[TILE];
#pragma unroll
            for (int j = 0; j < TILE; ++j) xv[j] = XBUF[xb][j][lane];

#pragma unroll
            for (int j = 0; j < TILE; ++j) {
                const float i_t = __fmul_rn(xv[j], w);
                vsyn = __fadd_rn(__fmul_rn(alpha, vsyn), i_t);
                const float va = __fadd_rn(__fmul_rn(alpha, vmem), vsyn);
                const bool fire = (va >= 1.0f);
                SBUF[sb][j][lane] = fire ? 1.0f : 0.0f;
                vmem = fire ? __fsub_rn(va, 1.0f) : va;   // == va - spk
            }
            SB();
            // publish spikes before the raw barrier (no implicit drain).
            asm volatile("s_waitcnt lgkmcnt(0)");
            SB();
            __builtin_amdgcn_s_barrier();
        }
    }
}

extern "C" void kernel_launch(void* const* d_in, const int* in_sizes, int n_in,
                              void* d_out, int out_size, void* d_ws, size_t ws_size,
                              hipStream_t stream) {
    const float* x = (const float*)d_in[0];
    const float* w = (const float*)d_in[1];
    float* out = (float*)d_out;

    dim3 grid(256);    // one block per CU; 64 sequences per block
    dim3 block(448);   // 1 consumer + 4 producer + 2 writer waves
    hipLaunchKernelGGL(exodus_ms_kernel, grid, block, 0, stream, x, w, out);
}